// Round 2
// baseline (404.895 us; speedup 1.0000x reference)
//
#include <hip/hip_runtime.h>
#include <hip/hip_bf16.h>
#include <cstdint>
#include <cstddef>

constexpr int B = 64, N = 2048, E = 512, D = 256, H = 256, K = 5, I = 768;

__device__ __forceinline__ float sg(float x) { return 1.0f / (1.0f + __expf(-x)); }

__device__ __forceinline__ void dot4(float4 v, const float* s, float& acc) {
  acc += v.x * s[0];
  acc += v.y * s[1];
  acc += v.z * s[2];
  acc += v.w * s[3];
}

// One block per batch element. Phase 1: GRU step + K MLPs -> arg = mean/scale.
// Phase 2: c[b,e] = sum_n (sig(n+.5-arg)-sig(n-.5-arg)) * enc[b,n,e],
// truncated at ceil(arg)+32 (tail < 1e-13, threshold is 6.25e-2).
__global__ __launch_bounds__(256) void fused(
    const float* __restrict__ enc, const float* __restrict__ dec,
    const float* __restrict__ h0,
    const float* __restrict__ Wih, const float* __restrict__ Whh,
    const float* __restrict__ bih, const float* __restrict__ bhh,
    const float* __restrict__ W1,  const float* __restrict__ b1,
    const float* __restrict__ W2,  const float* __restrict__ b2,
    float* __restrict__ out_c, float* __restrict__ out_h)
{
  __shared__ float xs[D], hs[H], hn[H], hid[K][H], pr[16];
  __shared__ float s_arg;
  const int b = blockIdx.x, t = threadIdx.x;
  xs[t] = dec[b * D + t];
  hs[t] = h0[b * H + t];
  __syncthreads();

  // gi = x @ W_ih.T + b_ih ; x = [dec_z, zeros(E)] -> only first 256 columns.
  // gh = h_prev @ W_hh.T + b_hh. Thread t owns h-index t for gates r,z,n.
  float gir = bih[t], giz = bih[H + t], gin = bih[2*H + t];
  float ghr = bhh[t], ghz = bhh[H + t], ghn = bhh[2*H + t];
  const float4* wr = reinterpret_cast<const float4*>(Wih + (size_t)t         * I);
  const float4* wz = reinterpret_cast<const float4*>(Wih + (size_t)(H + t)   * I);
  const float4* wn = reinterpret_cast<const float4*>(Wih + (size_t)(2*H + t) * I);
  const float4* ur = reinterpret_cast<const float4*>(Whh + (size_t)t         * H);
  const float4* uz = reinterpret_cast<const float4*>(Whh + (size_t)(H + t)   * H);
  const float4* un = reinterpret_cast<const float4*>(Whh + (size_t)(2*H + t) * H);
#pragma unroll 8
  for (int c = 0; c < 64; ++c) {
    dot4(wr[c], &xs[c*4], gir);
    dot4(wz[c], &xs[c*4], giz);
    dot4(wn[c], &xs[c*4], gin);
    dot4(ur[c], &hs[c*4], ghr);
    dot4(uz[c], &hs[c*4], ghz);
    dot4(un[c], &hs[c*4], ghn);
  }
  const float r = sg(gir + ghr);
  const float z = sg(giz + ghz);
  const float nn = tanhf(gin + r * ghn);
  const float hnew = (1.0f - z) * nn + z * hs[t];
  hn[t] = hnew;
  out_h[b * H + t] = hnew;
  __syncthreads();

  // hid[k][t] = tanh(W1[k,t,:] . h_new + b1[k,t])
#pragma unroll
  for (int k = 0; k < K; ++k) {
    float acc = b1[k * H + t];
    const float4* w = reinterpret_cast<const float4*>(W1 + ((size_t)k * H + t) * H);
#pragma unroll 8
    for (int c = 0; c < 64; ++c) dot4(w[c], &hn[c*4], acc);
    hid[k][t] = tanhf(acc);
  }
  __syncthreads();

  // params[k,p] = W2[k,p,:] . hid[k,:] + b2[k,p]; 15 dots, 16 threads each.
  if (t < 240) {
    const int g = t >> 4, sub = t & 15;
    const int k = g / 3, p = g % 3;
    float s = 0.0f;
#pragma unroll
    for (int c = 0; c < 16; ++c) {
      const int h = sub + 16 * c;
      s += hid[k][h] * W2[(k * 3 + p) * H + h];
    }
    s += __shfl_xor(s, 8, 16);
    s += __shfl_xor(s, 4, 16);
    s += __shfl_xor(s, 2, 16);
    s += __shfl_xor(s, 1, 16);
    if (sub == 0) pr[g] = s + b2[k * 3 + p];
  }
  __syncthreads();

  // mean = exp(p0), scale = exp(p1) (last component only survives);
  // arg = mean/scale = exp(p0 - p1). softmax weights sum to 1 -> drop out.
  if (t == 0) s_arg = __expf(pr[3 * (K - 1)] - pr[3 * (K - 1) + 1]);
  __syncthreads();

  // Phase 2: thread t owns columns 2t, 2t+1 (one float2 per row).
  const float arg = s_arg;
  const float lim = ceilf(arg) + 32.0f;
  int nmax = (lim < (float)N) ? (int)lim : N;  // also guards Inf/NaN arg
  if (nmax < 1) nmax = 1;

  const float2* src = reinterpret_cast<const float2*>(enc + (size_t)b * N * E) + t;
  float a0 = 0.0f, a1 = 0.0f;
#pragma unroll 4
  for (int n = 0; n < nmax; ++n) {
    const float fn = (float)n;
    const float an = sg(fn + 0.5f - arg) - sg(fn - 0.5f - arg);
    const float2 v = src[(size_t)n * (E / 2)];
    a0 += an * v.x;
    a1 += an * v.y;
  }
  out_c[b * E + 2 * t]     = a0;
  out_c[b * E + 2 * t + 1] = a1;
}

extern "C" void kernel_launch(void* const* d_in, const int* in_sizes, int n_in,
                              void* d_out, int out_size, void* d_ws, size_t ws_size,
                              hipStream_t stream) {
  const float* enc = (const float*)d_in[0];
  const float* dec = (const float*)d_in[1];
  const float* h0  = (const float*)d_in[2];
  const float* Wih = (const float*)d_in[3];
  const float* Whh = (const float*)d_in[4];
  const float* bih = (const float*)d_in[5];
  const float* bhh = (const float*)d_in[6];
  const float* W1  = (const float*)d_in[7];
  const float* b1  = (const float*)d_in[8];
  const float* W2  = (const float*)d_in[9];
  const float* b2  = (const float*)d_in[10];
  (void)in_sizes; (void)n_in; (void)out_size; (void)d_ws; (void)ws_size;

  float* out_c = (float*)d_out;            // (1, B, E) first
  float* out_h = out_c + (size_t)B * E;    // then (1, B, H)

  hipLaunchKernelGGL(fused, dim3(B), dim3(256), 0, stream,
                     enc, dec, h0, Wih, Whh, bih, bhh, W1, b1, W2, b2,
                     out_c, out_h);
}